// Round 20
// baseline (92.515 us; speedup 1.0000x reference)
//
#include <hip/hip_runtime.h>

#define BATCH 128
#define C 64
#define L 4096
#define K 31

#define NT 512               // 8 waves; block covers all of L in produce phase
#define NWAVE 8
#define CG 4                 // producer groups per batch
#define CPB (C / CG)         // 16 channels per block
#define RW 8                 // samples/outputs per lane
#define WTILE 512            // outputs per wave
#define SP_FLOATS ((long)CG * BATCH * L)          // 8 MB scratch

typedef float floatx4 __attribute__((ext_vector_type(4)));

__device__ __forceinline__ floatx4 ld4(const float* p) {
    return *reinterpret_cast<const floatx4*>(p);
}

// Persistent producer-consumer (r18 protocol, r19 compute, REGISTER FIX):
//  __launch_bounds__(512,4) -> VGPR cap 128 (loop needs ~70, no spill;
//  r18's (512,8) capped at 64 and spilled P[38]). Residency: 4 waves/EU
//  -> 2 blocks/CU x 256 = 512 = grid, all blocks resident -> spin safe.
#define KSTEP(k) { const float wk = wp[k];                              \
    P[(k)+0] += wk * o0.x; P[(k)+1] += wk * o0.y;                       \
    P[(k)+2] += wk * o0.z; P[(k)+3] += wk * o0.w;                       \
    P[(k)+4] += wk * o1.x; P[(k)+5] += wk * o1.y;                       \
    P[(k)+6] += wk * o1.z; P[(k)+7] += wk * o1.w; }

__global__ __launch_bounds__(NT, 4)
void revconv_persistent(const float* __restrict__ x,
                        const float* __restrict__ w,
                        float* __restrict__ Sp,
                        int* __restrict__ done,
                        float* __restrict__ out) {
    __shared__ float exL1[NWAVE][8];   // lane63's P[23..30]
    __shared__ float exL2a[NWAVE][8];  // lane62's P[31..37]
    __shared__ float exL2b[NWAVE][8];  // lane63's P[31..37]
    __shared__ float exR1[NWAVE][8];   // lane0's  P[7..14]
    __shared__ float exR2a[NWAVE][8];  // lane1's  P[0..6]
    __shared__ float exR2b[NWAVE][8];  // lane0's  P[0..6]

    const int tid  = threadIdx.x;
    const int wv   = tid >> 6;
    const int lane = tid & 63;
    const int bid  = blockIdx.x;          // 0..511
    const int b    = bid >> 2;            // 0..127
    const int cg   = bid & 3;             // 0..3
    const int l0   = wv * WTILE + lane * RW;
    const int i0   = cg * CPB;
    const float* xb = x + (long)b * C * L;

    // ================= produce (r19's proven scatter loop) =================
    float P[38] = {};   // P[j] <-> output l0 - 15 + j

    const float* xi = xb + (long)i0 * L + l0;
    floatx4 o0 = ld4(xi), o1 = ld4(xi + 4);

    for (int c = 0; c < CPB; ++c) {
        floatx4 n0 = o0, n1 = o1;
        if (c + 1 < CPB) { n0 = ld4(xi + L); n1 = ld4(xi + L + 4); }

        const float* wp = w + (i0 + c) * K;   // block-uniform -> s_load
        KSTEP(0)  KSTEP(1)  KSTEP(2)  KSTEP(3)  KSTEP(4)  KSTEP(5)
        KSTEP(6)  KSTEP(7)  KSTEP(8)  KSTEP(9)  KSTEP(10) KSTEP(11)
        KSTEP(12) KSTEP(13) KSTEP(14) KSTEP(15) KSTEP(16) KSTEP(17)
        KSTEP(18) KSTEP(19) KSTEP(20) KSTEP(21) KSTEP(22) KSTEP(23)
        KSTEP(24) KSTEP(25) KSTEP(26) KSTEP(27) KSTEP(28) KSTEP(29)
        KSTEP(30)

        o0 = n0; o1 = n1;
        xi += L;
    }

    // wave-edge partials to LDS (2-hop exchange, r13-proven)
    if (lane == 63) {
#pragma unroll
        for (int j = 0; j < 8; ++j) exL1[wv][j] = P[23 + j];
#pragma unroll
        for (int j = 0; j < 7; ++j) exL2b[wv][j] = P[31 + j];
    }
    if (lane == 62) {
#pragma unroll
        for (int j = 0; j < 7; ++j) exL2a[wv][j] = P[31 + j];
    }
    if (lane == 0) {
#pragma unroll
        for (int j = 0; j < 8; ++j) exR1[wv][j] = P[7 + j];
#pragma unroll
        for (int j = 0; j < 7; ++j) exR2b[wv][j] = P[j];
    }
    if (lane == 1) {
#pragma unroll
        for (int j = 0; j < 7; ++j) exR2a[wv][j] = P[j];
    }
    __syncthreads();

    float res[RW];
#pragma unroll
    for (int r = 0; r < RW; ++r) res[r] = P[15 + r];

#pragma unroll
    for (int r = 0; r < 8; ++r) {
        float v = __shfl_up(P[23 + r], 1, 64);
        if (lane == 0) v = (wv > 0) ? exL1[wv - 1][r] : 0.f;
        res[r] += v;
    }
#pragma unroll
    for (int r = 0; r < 7; ++r) {
        float v = __shfl_up(P[31 + r], 2, 64);
        if (lane == 0)      v = (wv > 0) ? exL2a[wv - 1][r] : 0.f;
        else if (lane == 1) v = (wv > 0) ? exL2b[wv - 1][r] : 0.f;
        res[r] += v;
    }
#pragma unroll
    for (int r = 0; r < 8; ++r) {
        float v = __shfl_down(P[7 + r], 1, 64);
        if (lane == 63) v = (wv < NWAVE - 1) ? exR1[wv + 1][r] : 0.f;
        res[r] += v;
    }
#pragma unroll
    for (int r = 1; r < 8; ++r) {
        float v = __shfl_down(P[r - 1], 2, 64);
        if (lane == 63)      v = (wv < NWAVE - 1) ? exR2a[wv + 1][r - 1] : 0.f;
        else if (lane == 62) v = (wv < NWAVE - 1) ? exR2b[wv + 1][r - 1] : 0.f;
        res[r] += v;
    }

    {
        floatx4 s0, s1;
        s0.x = res[0]; s0.y = res[1]; s0.z = res[2]; s0.w = res[3];
        s1.x = res[4]; s1.y = res[5]; s1.z = res[6]; s1.w = res[7];
        float* sp = Sp + ((long)cg * BATCH + b) * L + l0;
        *reinterpret_cast<floatx4*>(sp)     = s0;
        *reinterpret_cast<floatx4*>(sp + 4) = s1;
    }

    // ================= flag (release, agent scope; r18-proven) =================
    __syncthreads();   // drains vmcnt(0): all block stores complete before flag
    if (tid == 0)
        __hip_atomic_fetch_add(&done[b], 1, __ATOMIC_RELEASE, __HIP_MEMORY_SCOPE_AGENT);

    // ================= consume =================
    if (tid == 0) {
        while (__hip_atomic_load(&done[b], __ATOMIC_ACQUIRE, __HIP_MEMORY_SCOPE_AGENT) < CG)
            __builtin_amdgcn_s_sleep(1);
    }
    __syncthreads();

    // sum 4 planes at float4 columns tid and tid+512
    floatx4 va = 0.f, vb = 0.f;
#pragma unroll
    for (int p = 0; p < CG; ++p) {
        const float* pp = Sp + ((long)p * BATCH + b) * L + tid * 4;
        va += ld4(pp);
        vb += ld4(pp + 2048);
    }

    float* ob = out + ((long)b * C + cg * CPB) * L;
#pragma unroll
    for (int o = 0; o < CPB; ++o) {
        float* op = ob + (long)o * L + tid * 4;
        __builtin_nontemporal_store(va, reinterpret_cast<floatx4*>(op));
        __builtin_nontemporal_store(vb, reinterpret_cast<floatx4*>(op + 2048));
    }
}

// ---- Fallback (round-3 fused) if ws too small ----
#define FB_R 4
#define FB_TILE (256 * FB_R)
#define FB_WIN 36
__global__ __launch_bounds__(256)
void fused_kernel(const float* __restrict__ x,
                  const float* __restrict__ w,
                  float* __restrict__ out) {
    const int tid = threadIdx.x;
    const int tile = blockIdx.x;
    const int b = blockIdx.y;
    const int l0 = tile * FB_TILE + tid * FB_R;
    float acc[FB_R] = {0.f, 0.f, 0.f, 0.f};
    const float* xb = x + (long)b * C * L;
    const bool interior = (l0 >= 16) && (l0 + 20 <= L);
    if (interior) {
        const float* xw = xb + (l0 - 16);
#pragma unroll 2
        for (int i = 0; i < C; ++i) {
            float win[FB_WIN];
            const floatx4* p = reinterpret_cast<const floatx4*>(xw + (long)i * L);
#pragma unroll
            for (int j = 0; j < FB_WIN / 4; ++j)
                reinterpret_cast<floatx4*>(win)[j] = p[j];
            const float* wp = w + i * K;
#pragma unroll
            for (int k = 0; k < K; ++k) {
                const float wk = wp[k];
#pragma unroll
                for (int r = 0; r < FB_R; ++r)
                    acc[r] += wk * win[r + 31 - k];
            }
        }
    } else {
        for (int i = 0; i < C; ++i) {
            const float* xi = xb + (long)i * L;
            float win[FB_WIN];
#pragma unroll
            for (int j = 0; j < FB_WIN; ++j) {
                const int g = l0 - 16 + j;
                win[j] = (g >= 0 && g < L) ? xi[g] : 0.f;
            }
            const float* wp = w + i * K;
#pragma unroll
            for (int k = 0; k < K; ++k) {
                const float wk = wp[k];
#pragma unroll
                for (int r = 0; r < FB_R; ++r)
                    acc[r] += wk * win[r + 31 - k];
            }
        }
    }
    float* op = out + (long)b * C * L + l0;
    floatx4 v; v.x = acc[0]; v.y = acc[1]; v.z = acc[2]; v.w = acc[3];
#pragma unroll
    for (int o = 0; o < C; ++o)
        __builtin_nontemporal_store(v, reinterpret_cast<floatx4*>(op + (long)o * L));
}

extern "C" void kernel_launch(void* const* d_in, const int* in_sizes, int n_in,
                              void* d_out, int out_size, void* d_ws, size_t ws_size,
                              hipStream_t stream) {
    const float* x = (const float*)d_in[0];   // [B, C, L] fp32
    const float* w = (const float*)d_in[1];   // [C, C, K] fp32; o=0 slice used
    float* out = (float*)d_out;               // [B, C, L] fp32

    const size_t sp_bytes = SP_FLOATS * sizeof(float);        // 8 MB
    const size_t need = sp_bytes + BATCH * sizeof(int);
    if (ws_size >= need) {
        float* Sp  = (float*)d_ws;
        int* done  = (int*)((char*)d_ws + sp_bytes);
        hipMemsetAsync(done, 0, BATCH * sizeof(int), stream);  // reset flags each call
        revconv_persistent<<<BATCH * CG, NT, 0, stream>>>(x, w, Sp, done, out);
    } else {
        dim3 grid(L / FB_TILE, BATCH);
        fused_kernel<<<grid, 256, 0, stream>>>(x, w, out);
    }
}

// Round 21
// 59.155 us; speedup vs baseline: 1.5640x; 1.5640x over previous
//
#include <hip/hip_runtime.h>

// Problem constants (fixed by the reference)
#define BATCH 128
#define C 64
#define L 4096
#define K 31

#define NT 512               // 8 waves; one block covers all of L
#define NWAVE 8
#define CG 4                 // channel groups (blocks split over channels)
#define CPB (C / CG)         // 16 channels per block
#define RW 8                 // samples/outputs per lane
#define WTILE 512            // outputs per wave (64 lanes * RW); 8 waves = L

typedef float floatx4 __attribute__((ext_vector_type(4)));

__device__ __forceinline__ floatx4 ld4(const float* p) {
    return *reinterpret_cast<const floatx4*>(p);
}

// ---- K1: Sp[cg][b][l] = sum_{i in cg} sum_k w[i,k] * x[b,i,l+15-k]
// r19's scatter loop + 2-deep prefetch via a ROLLED x2-channel loop with
// explicit 3-set rotation (r15's failure was the full unroll, not the
// prefetch depth: ~990 issue-cycles of load cover vs 1-deep's ~496).
#define KS(k, q0, q1) { const float wk = wp[k];                          \
    P[(k)+0] += wk * q0.x; P[(k)+1] += wk * q0.y;                        \
    P[(k)+2] += wk * q0.z; P[(k)+3] += wk * q0.w;                        \
    P[(k)+4] += wk * q1.x; P[(k)+5] += wk * q1.y;                        \
    P[(k)+6] += wk * q1.z; P[(k)+7] += wk * q1.w; }
#define CHAN(q0, q1)                                                     \
    KS(0,q0,q1)  KS(1,q0,q1)  KS(2,q0,q1)  KS(3,q0,q1)  KS(4,q0,q1)      \
    KS(5,q0,q1)  KS(6,q0,q1)  KS(7,q0,q1)  KS(8,q0,q1)  KS(9,q0,q1)      \
    KS(10,q0,q1) KS(11,q0,q1) KS(12,q0,q1) KS(13,q0,q1) KS(14,q0,q1)     \
    KS(15,q0,q1) KS(16,q0,q1) KS(17,q0,q1) KS(18,q0,q1) KS(19,q0,q1)     \
    KS(20,q0,q1) KS(21,q0,q1) KS(22,q0,q1) KS(23,q0,q1) KS(24,q0,q1)     \
    KS(25,q0,q1) KS(26,q0,q1) KS(27,q0,q1) KS(28,q0,q1) KS(29,q0,q1)     \
    KS(30,q0,q1)

__global__ __launch_bounds__(NT, 2)
void computeS_kernel(const float* __restrict__ x,
                     const float* __restrict__ w,
                     float* __restrict__ Sp) {
    __shared__ float exL1[NWAVE][8];   // lane63's P[23..30]
    __shared__ float exL2a[NWAVE][8];  // lane62's P[31..37]
    __shared__ float exL2b[NWAVE][8];  // lane63's P[31..37]
    __shared__ float exR1[NWAVE][8];   // lane0's  P[7..14]
    __shared__ float exR2a[NWAVE][8];  // lane1's  P[0..6]
    __shared__ float exR2b[NWAVE][8];  // lane0's  P[0..6]

    const int tid  = threadIdx.x;
    const int wv   = tid >> 6;
    const int lane = tid & 63;
    const int b    = blockIdx.x;          // 0..127
    const int cg   = blockIdx.y;          // 0..3
    const int l0   = wv * WTILE + lane * RW;
    const int i0   = cg * CPB;
    const float* xb = x + (long)b * C * L;

    float P[38] = {};   // P[j] <-> output l0 - 15 + j

    const float* xi = xb + (long)i0 * L + l0;   // channel-c row (+l0)
    floatx4 X0 = ld4(xi),     X1 = ld4(xi + 4);       // data(c)
    floatx4 Y0 = ld4(xi + L), Y1 = ld4(xi + L + 4);   // data(c+1)

    for (int c = 0; c < CPB; c += 2) {
        // prefetch data(c+2) into Z (2-deep relative to its consumption)
        floatx4 Z0 = 0.f, Z1 = 0.f;
        if (c + 2 < CPB) { Z0 = ld4(xi + 2 * (long)L); Z1 = ld4(xi + 2 * (long)L + 4); }

        { const float* wp = w + (i0 + c) * K; CHAN(X0, X1) }

        // prefetch data(c+3) into Wv
        floatx4 W0v = 0.f, W1v = 0.f;
        if (c + 3 < CPB) { W0v = ld4(xi + 3 * (long)L); W1v = ld4(xi + 3 * (long)L + 4); }

        { const float* wp = w + (i0 + c + 1) * K; CHAN(Y0, Y1) }

        X0 = Z0;  X1 = Z1;      // data(c+2)
        Y0 = W0v; Y1 = W1v;     // data(c+3)
        xi += 2 * (long)L;
    }

    // ---- wave-edge partials to LDS (once per kernel; r13-proven) ----
    if (lane == 63) {
#pragma unroll
        for (int j = 0; j < 8; ++j) exL1[wv][j] = P[23 + j];
#pragma unroll
        for (int j = 0; j < 7; ++j) exL2b[wv][j] = P[31 + j];
    }
    if (lane == 62) {
#pragma unroll
        for (int j = 0; j < 7; ++j) exL2a[wv][j] = P[31 + j];
    }
    if (lane == 0) {
#pragma unroll
        for (int j = 0; j < 8; ++j) exR1[wv][j] = P[7 + j];
#pragma unroll
        for (int j = 0; j < 7; ++j) exR2b[wv][j] = P[j];
    }
    if (lane == 1) {
#pragma unroll
        for (int j = 0; j < 7; ++j) exR2a[wv][j] = P[j];
    }
    __syncthreads();

    float res[RW];
#pragma unroll
    for (int r = 0; r < RW; ++r) res[r] = P[15 + r];

    // up1: lane-1's P[23+r]
#pragma unroll
    for (int r = 0; r < 8; ++r) {
        float v = __shfl_up(P[23 + r], 1, 64);
        if (lane == 0) v = (wv > 0) ? exL1[wv - 1][r] : 0.f;
        res[r] += v;
    }
    // up2: lane-2's P[31+r], r=0..6
#pragma unroll
    for (int r = 0; r < 7; ++r) {
        float v = __shfl_up(P[31 + r], 2, 64);
        if (lane == 0)      v = (wv > 0) ? exL2a[wv - 1][r] : 0.f;
        else if (lane == 1) v = (wv > 0) ? exL2b[wv - 1][r] : 0.f;
        res[r] += v;
    }
    // down1: lane+1's P[7+r]
#pragma unroll
    for (int r = 0; r < 8; ++r) {
        float v = __shfl_down(P[7 + r], 1, 64);
        if (lane == 63) v = (wv < NWAVE - 1) ? exR1[wv + 1][r] : 0.f;
        res[r] += v;
    }
    // down2: lane+2's P[r-1], r=1..7
#pragma unroll
    for (int r = 1; r < 8; ++r) {
        float v = __shfl_down(P[r - 1], 2, 64);
        if (lane == 63)      v = (wv < NWAVE - 1) ? exR2a[wv + 1][r - 1] : 0.f;
        else if (lane == 62) v = (wv < NWAVE - 1) ? exR2b[wv + 1][r - 1] : 0.f;
        res[r] += v;
    }

    floatx4 s0, s1;
    s0.x = res[0]; s0.y = res[1]; s0.z = res[2]; s0.w = res[3];
    s1.x = res[4]; s1.y = res[5]; s1.z = res[6]; s1.w = res[7];
    float* sp = Sp + ((long)cg * BATCH + b) * L + l0;
    *reinterpret_cast<floatx4*>(sp)     = s0;
    *reinterpret_cast<floatx4*>(sp + 4) = s1;
}

// ---- K2: out[b,o,l] = sum_cg Sp[cg][b][l] — dense streaming broadcast.
__global__ __launch_bounds__(256)
void broadcast_kernel(const float* __restrict__ Sp,
                      float* __restrict__ out) {
    const int lane = threadIdx.x & 63;
    const int og   = threadIdx.x >> 6;            // 0..3
    const int b    = blockIdx.y;
    const int l4   = blockIdx.x * 64 + lane;      // float4 column index
    const long sbase = (long)b * L + (long)l4 * 4;

    floatx4 v = *reinterpret_cast<const floatx4*>(Sp + sbase);
#pragma unroll
    for (int cg = 1; cg < CG; ++cg)
        v += *reinterpret_cast<const floatx4*>(Sp + (long)cg * BATCH * L + sbase);

    float* ob = out + ((long)b * C + og * 16) * L + (long)l4 * 4;
#pragma unroll
    for (int o = 0; o < 16; ++o)
        __builtin_nontemporal_store(v, reinterpret_cast<floatx4*>(ob + (long)o * L));
}

// ---- Fallback (proven round-3 fused kernel) if ws too small ----
#define FB_R 4
#define FB_TILE (256 * FB_R)
#define FB_WIN 36
__global__ __launch_bounds__(256)
void fused_kernel(const float* __restrict__ x,
                  const float* __restrict__ w,
                  float* __restrict__ out) {
    const int tid = threadIdx.x;
    const int tile = blockIdx.x;
    const int b = blockIdx.y;
    const int l0 = tile * FB_TILE + tid * FB_R;
    float acc[FB_R] = {0.f, 0.f, 0.f, 0.f};
    const float* xb = x + (long)b * C * L;
    const bool interior = (l0 >= 16) && (l0 + 20 <= L);
    if (interior) {
        const float* xw = xb + (l0 - 16);
#pragma unroll 2
        for (int i = 0; i < C; ++i) {
            float win[FB_WIN];
            const floatx4* p = reinterpret_cast<const floatx4*>(xw + (long)i * L);
#pragma unroll
            for (int j = 0; j < FB_WIN / 4; ++j)
                reinterpret_cast<floatx4*>(win)[j] = p[j];
            const float* wp = w + i * K;
#pragma unroll
            for (int k = 0; k < K; ++k) {
                const float wk = wp[k];
#pragma unroll
                for (int r = 0; r < FB_R; ++r)
                    acc[r] += wk * win[r + 31 - k];
            }
        }
    } else {
        for (int i = 0; i < C; ++i) {
            const float* xi = xb + (long)i * L;
            float win[FB_WIN];
#pragma unroll
            for (int j = 0; j < FB_WIN; ++j) {
                const int g = l0 - 16 + j;
                win[j] = (g >= 0 && g < L) ? xi[g] : 0.f;
            }
            const float* wp = w + i * K;
#pragma unroll
            for (int k = 0; k < K; ++k) {
                const float wk = wp[k];
#pragma unroll
                for (int r = 0; r < FB_R; ++r)
                    acc[r] += wk * win[r + 31 - k];
            }
        }
    }
    float* op = out + (long)b * C * L + l0;
    floatx4 v; v.x = acc[0]; v.y = acc[1]; v.z = acc[2]; v.w = acc[3];
#pragma unroll
    for (int o = 0; o < C; ++o)
        __builtin_nontemporal_store(v, reinterpret_cast<floatx4*>(op + (long)o * L));
}

extern "C" void kernel_launch(void* const* d_in, const int* in_sizes, int n_in,
                              void* d_out, int out_size, void* d_ws, size_t ws_size,
                              hipStream_t stream) {
    const float* x = (const float*)d_in[0];   // [B, C, L] fp32
    const float* w = (const float*)d_in[1];   // [C, C, K] fp32; o=0 slice used
    float* out = (float*)d_out;               // [B, C, L] fp32

    const size_t sp_bytes = (size_t)CG * BATCH * L * sizeof(float);   // 8 MB
    if (ws_size >= sp_bytes) {
        float* Sp = (float*)d_ws;
        dim3 grid1(BATCH, CG);                    // 128 x 4 = 512 blocks x 8 waves
        computeS_kernel<<<grid1, NT, 0, stream>>>(x, w, Sp);
        dim3 grid2(L / 256, BATCH);               // 2048 blocks
        broadcast_kernel<<<grid2, 256, 0, stream>>>(Sp, out);
    } else {
        dim3 grid(L / FB_TILE, BATCH);
        fused_kernel<<<grid, 256, 0, stream>>>(x, w, out);
    }
}

// Round 22
// 58.309 us; speedup vs baseline: 1.5866x; 1.0145x over previous
//
#include <hip/hip_runtime.h>

// Problem constants (fixed by the reference)
#define BATCH 128
#define C 64
#define L 4096
#define K 31

#define NT 512               // 8 waves; one block covers all of L
#define NWAVE 8
#define CG 4                 // channel groups (blocks split over channels)
#define CPB (C / CG)         // 16 channels per block
#define RW 8                 // samples/outputs per lane
#define WTILE 512            // outputs per wave (64 lanes * RW); 8 waves = L

typedef float floatx4 __attribute__((ext_vector_type(4)));
typedef unsigned short ushortx8 __attribute__((ext_vector_type(8)));
typedef unsigned short ushortx4 __attribute__((ext_vector_type(4)));

__device__ __forceinline__ floatx4 ld4(const float* p) {
    return *reinterpret_cast<const floatx4*>(p);
}

__device__ __forceinline__ unsigned short f2bf(float f) {   // RNE
    unsigned int u = __float_as_uint(f);
    return (unsigned short)((u + 0x7FFFu + ((u >> 16) & 1u)) >> 16);
}
__device__ __forceinline__ float bf2f(unsigned short h) {
    return __uint_as_float(((unsigned int)h) << 16);
}

// ---- K1: SpH[cg][b][l] (bf16) = sum_{i in cg} sum_k w[i,k] * x[b,i,l+15-k]
// r19's proven scatter loop (CG=4, 1-deep prefetch, 2-hop end exchange);
// partials stored as bf16 to halve the scratch round-trip (8->4 MB each way).
#define KSTEP(k) { const float wk = wp[k];                              \
    P[(k)+0] += wk * o0.x; P[(k)+1] += wk * o0.y;                       \
    P[(k)+2] += wk * o0.z; P[(k)+3] += wk * o0.w;                       \
    P[(k)+4] += wk * o1.x; P[(k)+5] += wk * o1.y;                       \
    P[(k)+6] += wk * o1.z; P[(k)+7] += wk * o1.w; }

__global__ __launch_bounds__(NT, 2)
void computeS_kernel(const float* __restrict__ x,
                     const float* __restrict__ w,
                     unsigned short* __restrict__ SpH) {
    __shared__ float exL1[NWAVE][8];   // lane63's P[23..30]
    __shared__ float exL2a[NWAVE][8];  // lane62's P[31..37]
    __shared__ float exL2b[NWAVE][8];  // lane63's P[31..37]
    __shared__ float exR1[NWAVE][8];   // lane0's  P[7..14]
    __shared__ float exR2a[NWAVE][8];  // lane1's  P[0..6]
    __shared__ float exR2b[NWAVE][8];  // lane0's  P[0..6]

    const int tid  = threadIdx.x;
    const int wv   = tid >> 6;
    const int lane = tid & 63;
    const int b    = blockIdx.x;          // 0..127
    const int cg   = blockIdx.y;          // 0..3
    const int l0   = wv * WTILE + lane * RW;
    const int i0   = cg * CPB;
    const float* xb = x + (long)b * C * L;

    float P[38] = {};   // P[j] <-> output l0 - 15 + j

    const float* xi = xb + (long)i0 * L + l0;
    floatx4 o0 = ld4(xi), o1 = ld4(xi + 4);

    for (int c = 0; c < CPB; ++c) {
        // 1-deep prefetch of next channel's own samples
        floatx4 n0 = o0, n1 = o1;
        if (c + 1 < CPB) { n0 = ld4(xi + L); n1 = ld4(xi + L + 4); }

        const float* wp = w + (i0 + c) * K;   // block-uniform -> s_load
        KSTEP(0)  KSTEP(1)  KSTEP(2)  KSTEP(3)  KSTEP(4)  KSTEP(5)
        KSTEP(6)  KSTEP(7)  KSTEP(8)  KSTEP(9)  KSTEP(10) KSTEP(11)
        KSTEP(12) KSTEP(13) KSTEP(14) KSTEP(15) KSTEP(16) KSTEP(17)
        KSTEP(18) KSTEP(19) KSTEP(20) KSTEP(21) KSTEP(22) KSTEP(23)
        KSTEP(24) KSTEP(25) KSTEP(26) KSTEP(27) KSTEP(28) KSTEP(29)
        KSTEP(30)

        o0 = n0; o1 = n1;
        xi += L;
    }

    // ---- wave-edge partials to LDS (once per kernel; r13-proven) ----
    if (lane == 63) {
#pragma unroll
        for (int j = 0; j < 8; ++j) exL1[wv][j] = P[23 + j];
#pragma unroll
        for (int j = 0; j < 7; ++j) exL2b[wv][j] = P[31 + j];
    }
    if (lane == 62) {
#pragma unroll
        for (int j = 0; j < 7; ++j) exL2a[wv][j] = P[31 + j];
    }
    if (lane == 0) {
#pragma unroll
        for (int j = 0; j < 8; ++j) exR1[wv][j] = P[7 + j];
#pragma unroll
        for (int j = 0; j < 7; ++j) exR2b[wv][j] = P[j];
    }
    if (lane == 1) {
#pragma unroll
        for (int j = 0; j < 7; ++j) exR2a[wv][j] = P[j];
    }
    __syncthreads();

    float res[RW];
#pragma unroll
    for (int r = 0; r < RW; ++r) res[r] = P[15 + r];

    // up1: lane-1's P[23+r]   (wave edge via LDS; grid edge -> 0)
#pragma unroll
    for (int r = 0; r < 8; ++r) {
        float v = __shfl_up(P[23 + r], 1, 64);
        if (lane == 0) v = (wv > 0) ? exL1[wv - 1][r] : 0.f;
        res[r] += v;
    }
    // up2: lane-2's P[31+r], r=0..6
#pragma unroll
    for (int r = 0; r < 7; ++r) {
        float v = __shfl_up(P[31 + r], 2, 64);
        if (lane == 0)      v = (wv > 0) ? exL2a[wv - 1][r] : 0.f;
        else if (lane == 1) v = (wv > 0) ? exL2b[wv - 1][r] : 0.f;
        res[r] += v;
    }
    // down1: lane+1's P[7+r]
#pragma unroll
    for (int r = 0; r < 8; ++r) {
        float v = __shfl_down(P[7 + r], 1, 64);
        if (lane == 63) v = (wv < NWAVE - 1) ? exR1[wv + 1][r] : 0.f;
        res[r] += v;
    }
    // down2: lane+2's P[r-1], r=1..7
#pragma unroll
    for (int r = 1; r < 8; ++r) {
        float v = __shfl_down(P[r - 1], 2, 64);
        if (lane == 63)      v = (wv < NWAVE - 1) ? exR2a[wv + 1][r - 1] : 0.f;
        else if (lane == 62) v = (wv < NWAVE - 1) ? exR2b[wv + 1][r - 1] : 0.f;
        res[r] += v;
    }

    // pack to bf16 (RNE) and store 16 B
    ushortx8 hv;
#pragma unroll
    for (int r = 0; r < RW; ++r) hv[r] = f2bf(res[r]);
    *reinterpret_cast<ushortx8*>(SpH + ((long)cg * BATCH + b) * L + l0) = hv;
}

// ---- K2: out[b,o,l] = sum_cg bf2f(SpH[cg][b][l]) — dense streaming broadcast.
__global__ __launch_bounds__(256)
void broadcast_kernel(const unsigned short* __restrict__ SpH,
                      float* __restrict__ out) {
    const int lane = threadIdx.x & 63;
    const int og   = threadIdx.x >> 6;            // 0..3
    const int b    = blockIdx.y;
    const int l4   = blockIdx.x * 64 + lane;      // float4 column index
    const long sbase = (long)b * L + (long)l4 * 4;

    floatx4 v = 0.f;
#pragma unroll
    for (int cg = 0; cg < CG; ++cg) {
        const ushortx4 h = *reinterpret_cast<const ushortx4*>(SpH + (long)cg * BATCH * L + sbase);
        v.x += bf2f(h.x); v.y += bf2f(h.y); v.z += bf2f(h.z); v.w += bf2f(h.w);
    }

    float* ob = out + ((long)b * C + og * 16) * L + (long)l4 * 4;
#pragma unroll
    for (int o = 0; o < 16; ++o)
        __builtin_nontemporal_store(v, reinterpret_cast<floatx4*>(ob + (long)o * L));
}

// ---- Fallback (proven round-3 fused kernel) if ws too small ----
#define FB_R 4
#define FB_TILE (256 * FB_R)
#define FB_WIN 36
__global__ __launch_bounds__(256)
void fused_kernel(const float* __restrict__ x,
                  const float* __restrict__ w,
                  float* __restrict__ out) {
    const int tid = threadIdx.x;
    const int tile = blockIdx.x;
    const int b = blockIdx.y;
    const int l0 = tile * FB_TILE + tid * FB_R;
    float acc[FB_R] = {0.f, 0.f, 0.f, 0.f};
    const float* xb = x + (long)b * C * L;
    const bool interior = (l0 >= 16) && (l0 + 20 <= L);
    if (interior) {
        const float* xw = xb + (l0 - 16);
#pragma unroll 2
        for (int i = 0; i < C; ++i) {
            float win[FB_WIN];
            const floatx4* p = reinterpret_cast<const floatx4*>(xw + (long)i * L);
#pragma unroll
            for (int j = 0; j < FB_WIN / 4; ++j)
                reinterpret_cast<floatx4*>(win)[j] = p[j];
            const float* wp = w + i * K;
#pragma unroll
            for (int k = 0; k < K; ++k) {
                const float wk = wp[k];
#pragma unroll
                for (int r = 0; r < FB_R; ++r)
                    acc[r] += wk * win[r + 31 - k];
            }
        }
    } else {
        for (int i = 0; i < C; ++i) {
            const float* xi = xb + (long)i * L;
            float win[FB_WIN];
#pragma unroll
            for (int j = 0; j < FB_WIN; ++j) {
                const int g = l0 - 16 + j;
                win[j] = (g >= 0 && g < L) ? xi[g] : 0.f;
            }
            const float* wp = w + i * K;
#pragma unroll
            for (int k = 0; k < K; ++k) {
                const float wk = wp[k];
#pragma unroll
                for (int r = 0; r < FB_R; ++r)
                    acc[r] += wk * win[r + 31 - k];
            }
        }
    }
    float* op = out + (long)b * C * L + l0;
    floatx4 v; v.x = acc[0]; v.y = acc[1]; v.z = acc[2]; v.w = acc[3];
#pragma unroll
    for (int o = 0; o < C; ++o)
        __builtin_nontemporal_store(v, reinterpret_cast<floatx4*>(op + (long)o * L));
}

extern "C" void kernel_launch(void* const* d_in, const int* in_sizes, int n_in,
                              void* d_out, int out_size, void* d_ws, size_t ws_size,
                              hipStream_t stream) {
    const float* x = (const float*)d_in[0];   // [B, C, L] fp32
    const float* w = (const float*)d_in[1];   // [C, C, K] fp32; o=0 slice used
    float* out = (float*)d_out;               // [B, C, L] fp32

    const size_t sp_bytes = (size_t)CG * BATCH * L * sizeof(unsigned short);   // 4 MB
    if (ws_size >= sp_bytes) {
        unsigned short* SpH = (unsigned short*)d_ws;
        dim3 grid1(BATCH, CG);                    // 128 x 4 = 512 blocks x 8 waves
        computeS_kernel<<<grid1, NT, 0, stream>>>(x, w, SpH);
        dim3 grid2(L / 256, BATCH);               // 2048 blocks
        broadcast_kernel<<<grid2, 256, 0, stream>>>(SpH, out);
    } else {
        dim3 grid(L / FB_TILE, BATCH);
        fused_kernel<<<grid, 256, 0, stream>>>(x, w, out);
    }
}